// Round 3
// baseline (4292.223 us; speedup 1.0000x reference)
//
#include <hip/hip_runtime.h>

#define NPART 4096
#define E_TOT 262144
#define HID   128
#define FDOF  6
#define EPB   4                       // edges per block-iteration
#define NTILES (E_TOT / EPB)          // 65536

// Zero d_out with a kernel (NOT hipMemsetAsync): kernel nodes are reliably
// graph-captured in stream order. Round 2 post-mortem: memset-based init
// left d_out in a corrupt state after the timing harness's replay+tripwire
// launch pattern (post-timing absmax ~= max|ref|).
__global__ void pairvel_zero_kernel(float* __restrict__ out, int n) {
    const int i = blockIdx.x * blockDim.x + threadIdx.x;
    if (i < n) out[i] = 0.0f;
}

// Fit under the DEFAULT 256-VGPR budget with no spill (round 1 spilled at
// EPB=8; round 2's (128,1)/512-VGPR config was implicated in a replay
// failure). EPB=4 cuts live acc/temps; ~190 arch VGPRs needed.
__global__ __launch_bounds__(128, 2) void pairvel_fp32_kernel(
    const float* __restrict__ rel,       // [N,N,3]
    const int*   __restrict__ tgt,       // [E]
    const int*   __restrict__ src,       // [E]
    const float* __restrict__ force,     // [N,6]
    const float* __restrict__ visc,      // [1]
    const float* __restrict__ medianp,   // [1]
    const float* __restrict__ contactp,  // [1]
    const float* __restrict__ W1,        // [19,128]
    const float* __restrict__ b1,        // [128]
    const float* __restrict__ W2,        // [128,128]
    const float* __restrict__ b2,        // [128]
    const float* __restrict__ W3,        // [128,6]
    const float* __restrict__ b3,        // [6]
    float* __restrict__ out)             // [N,6]
{
    const int j    = threadIdx.x;   // hidden unit owned by this thread
    const int lane = j & 63;
    const int wid  = j >> 6;

    // ---- weights in registers: thread j holds column j of W1/W2, row j of W3
    float W1c[20], W2c[HID], W3r[FDOF];
    #pragma unroll
    for (int i = 0; i < 19; ++i) W1c[i] = W1[i * HID + j];
    W1c[19] = 0.f;
    #pragma unroll
    for (int k = 0; k < HID; ++k) W2c[k] = W2[k * HID + j];
    #pragma unroll
    for (int d = 0; d < FDOF; ++d) W3r[d] = W3[j * FDOF + d];
    const float b1j = b1[j], b2j = b2[j];
    const float inv_mu  = 1.0f / visc[0];
    const float median  = medianp[0];
    const float contact = contactp[0];

    __shared__ __align__(16) float x_lds[EPB][20];    // 19 feats + zero pad
    __shared__ __align__(16) float h1_lds[EPB][132];  // padded row
    __shared__ float vpart[EPB][FDOF][2];

    for (int tile = blockIdx.x; tile < NTILES; tile += gridDim.x) {
        const int e0 = tile * EPB;

        // ---- gather + feature build into LDS --------------------------------
        for (int t = j; t < EPB * 20; t += 128) {
            const int e = t / 20, i = t % 20;
            float val = 0.f;
            if (i < 19) {
                const int eg = e0 + e;
                const int tg = tgt[eg], sg = src[eg];
                if (i < 7) {
                    const float* rp = rel + ((size_t)tg * NPART + sg) * 3;
                    if (i < 3) {
                        val = rp[i];
                    } else {
                        const float x0 = rp[0], x1 = rp[1], x2 = rp[2];
                        const float dist =
                            fmaxf(sqrtf(x0*x0 + x1*x1 + x2*x2), 1e-8f);
                        if (i == 3) val = dist;
                        else if (i == 6) val = dist - contact;
                        else { float rs = dist - median; rs *= rs;
                               val = (i == 4) ? rs : rs * rs; }
                    }
                } else if (i < 13) {
                    val = force[tg * FDOF + (i - 7)];
                } else {
                    val = force[sg * FDOF + (i - 13)];
                }
            }
            x_lds[e][i] = val;
        }
        __syncthreads();

        // ---- layer 1: h1 = relu(x @ W1 + b1) --------------------------------
        #pragma unroll
        for (int e = 0; e < EPB; ++e) {
            float a = b1j;
            #pragma unroll
            for (int q = 0; q < 5; ++q) {
                const float4 xv =
                    *reinterpret_cast<const float4*>(&x_lds[e][q * 4]);
                a = fmaf(xv.x, W1c[q*4+0], a);
                a = fmaf(xv.y, W1c[q*4+1], a);
                a = fmaf(xv.z, W1c[q*4+2], a);
                a = fmaf(xv.w, W1c[q*4+3], a);
            }
            h1_lds[e][j] = fmaxf(a, 0.f);
        }
        __syncthreads();

        // ---- layer 2: h2 = relu(h1 @ W2 + b2), EPB independent chains -------
        float acc[EPB];
        #pragma unroll
        for (int e = 0; e < EPB; ++e) acc[e] = b2j;
        #pragma unroll
        for (int kq = 0; kq < HID / 4; ++kq) {
            #pragma unroll
            for (int e = 0; e < EPB; ++e) {
                const float4 hv =
                    *reinterpret_cast<const float4*>(&h1_lds[e][kq * 4]);
                acc[e] = fmaf(hv.x, W2c[kq*4+0], acc[e]);
                acc[e] = fmaf(hv.y, W2c[kq*4+1], acc[e]);
                acc[e] = fmaf(hv.z, W2c[kq*4+2], acc[e]);
                acc[e] = fmaf(hv.w, W2c[kq*4+3], acc[e]);
            }
        }

        // ---- layer 3: vel = (h2 @ W3 + b3)/mu, butterfly reduce over j ------
        #pragma unroll
        for (int e = 0; e < EPB; ++e) {
            const float h2 = fmaxf(acc[e], 0.f);
            float pd[FDOF];
            #pragma unroll
            for (int d = 0; d < FDOF; ++d) pd[d] = h2 * W3r[d];
            #pragma unroll
            for (int m = 1; m < 64; m <<= 1) {
                #pragma unroll
                for (int d = 0; d < FDOF; ++d)
                    pd[d] += __shfl_xor(pd[d], m);
            }
            if (lane == 0) {
                #pragma unroll
                for (int d = 0; d < FDOF; ++d) vpart[e][d][wid] = pd[d];
            }
        }
        __syncthreads();

        // ---- combine 2 waves, scale, scatter-add ----------------------------
        if (j < EPB * FDOF) {
            const int e = j / FDOF, d = j % FDOF;
            const float v =
                (vpart[e][d][0] + vpart[e][d][1] + b3[d]) * inv_mu;
            atomicAdd(&out[(size_t)tgt[e0 + e] * FDOF + d], v);
        }
        __syncthreads();
    }
}

extern "C" void kernel_launch(void* const* d_in, const int* in_sizes, int n_in,
                              void* d_out, int out_size, void* d_ws, size_t ws_size,
                              hipStream_t stream) {
    const float* rel   = (const float*)d_in[0];
    const int*   tgt   = (const int*)d_in[1];
    const int*   src   = (const int*)d_in[2];
    const float* force = (const float*)d_in[3];
    const float* visc  = (const float*)d_in[4];
    const float* med   = (const float*)d_in[5];
    const float* con   = (const float*)d_in[6];
    const float* W1    = (const float*)d_in[7];
    const float* b1    = (const float*)d_in[8];
    const float* W2    = (const float*)d_in[9];
    const float* b2    = (const float*)d_in[10];
    const float* W3    = (const float*)d_in[11];
    const float* b3    = (const float*)d_in[12];
    float* out = (float*)d_out;

    pairvel_zero_kernel<<<(out_size + 255) / 256, 256, 0, stream>>>(out, out_size);
    pairvel_fp32_kernel<<<2048, 128, 0, stream>>>(
        rel, tgt, src, force, visc, med, con, W1, b1, W2, b2, W3, b3, out);
}

// Round 4
// 47.626 us; speedup vs baseline: 90.1234x; 90.1234x over previous
//
#include <hip/hip_runtime.h>

#define NPART 4096
#define E_TOT 262144
#define HID   128
#define FDOF  6
#define BM    64                 // edges per block-iteration
#define NIT   (E_TOT / BM)       // 4096
#define GRID  1024
#define XPAD  40                 // bf16 per X row (cols 0..31 used, 16B-aligned rows)
#define HPAD  136                // bf16 per H row (cols 0..127 used; 272B rows)

typedef __bf16 bf16x8 __attribute__((ext_vector_type(8)));
typedef float  f32x4  __attribute__((ext_vector_type(4)));

__global__ void pairvel_zero_kernel(float* __restrict__ out, int n) {
    const int i = blockIdx.x * blockDim.x + threadIdx.x;
    if (i < n) out[i] = 0.0f;
}

// 4-wave block; wave w owns hidden cols [32w,32w+32) for L1/L2 and edge rows
// [16w,16w+16) for L3. Weights live as per-wave MFMA B-fragments (56 VGPRs);
// activations round-trip through LDS. No per-thread big arrays -> no spill.
__global__ __launch_bounds__(256) void pairvel_mfma_kernel(
    const float* __restrict__ rel,       // [N,N,3]
    const int*   __restrict__ tgt,       // [E]
    const int*   __restrict__ src,       // [E]
    const float* __restrict__ force,     // [N,6]
    const float* __restrict__ visc,
    const float* __restrict__ medianp,
    const float* __restrict__ contactp,
    const float* __restrict__ W1,        // [19,128]
    const float* __restrict__ b1,        // [128]
    const float* __restrict__ W2,        // [128,128]
    const float* __restrict__ b2,        // [128]
    const float* __restrict__ W3,        // [128,6]
    const float* __restrict__ b3,        // [6]
    float* __restrict__ out)             // [N,6]
{
    const int tid = threadIdx.x;
    const int w   = tid >> 6;     // wave 0..3
    const int l   = tid & 63;     // lane
    const int l15 = l & 15;
    const int lhi = l >> 4;       // 0..3

    // ---- weight fragments (B operand: lane l holds W[kt*32+lhi*8+r][n16+l15])
    bf16x8 w1f[2], w2f[4][2], w3f[4];
    #pragma unroll
    for (int nb = 0; nb < 2; ++nb) {
        const int n = (2 * w + nb) * 16 + l15;
        #pragma unroll
        for (int r = 0; r < 8; ++r) {
            const int k = lhi * 8 + r;
            w1f[nb][r] = (k < 19) ? (__bf16)W1[k * HID + n] : (__bf16)0.0f;
        }
    }
    #pragma unroll
    for (int kt = 0; kt < 4; ++kt)
        #pragma unroll
        for (int nb = 0; nb < 2; ++nb) {
            const int n = (2 * w + nb) * 16 + l15;
            #pragma unroll
            for (int r = 0; r < 8; ++r)
                w2f[kt][nb][r] = (__bf16)W2[(kt * 32 + lhi * 8 + r) * HID + n];
        }
    #pragma unroll
    for (int kt = 0; kt < 4; ++kt)
        #pragma unroll
        for (int r = 0; r < 8; ++r) {
            const int k = kt * 32 + lhi * 8 + r;
            w3f[kt][r] = (l15 < FDOF) ? (__bf16)W3[k * FDOF + l15] : (__bf16)0.0f;
        }

    const float b1v0 = b1[(2 * w) * 16 + l15];
    const float b1v1 = b1[(2 * w + 1) * 16 + l15];
    const float b2v0 = b2[(2 * w) * 16 + l15];
    const float b2v1 = b2[(2 * w + 1) * 16 + l15];
    const float b3v  = (l15 < FDOF) ? b3[l15] : 0.0f;
    const float inv_mu  = 1.0f / visc[0];
    const float median  = medianp[0];
    const float contact = contactp[0];

    __shared__ __align__(16) __bf16 Xs[BM][XPAD];
    __shared__ __align__(16) __bf16 H1s[BM][HPAD];
    __shared__ __align__(16) __bf16 H2s[BM][HPAD];
    __shared__ int tgts[BM];

    // zero X pad cols 19..31 once (rewritten cols are 0..18 each iter)
    for (int t = tid; t < BM * 13; t += 256) {
        const int e = t / 13, c = 19 + t % 13;
        Xs[e][c] = (__bf16)0.0f;
    }

    for (int it = blockIdx.x; it < NIT; it += GRID) {
        const int e0 = it * BM;
        __syncthreads();   // (A) prev-iter readers done before overwrite

        // ---- build X features (bf16) ---------------------------------------
        if (tid < BM) {
            const int e = tid, eg = e0 + e;
            const int tg = tgt[eg], sg = src[eg];
            tgts[e] = tg;
            const float* rp = rel + ((size_t)tg * NPART + sg) * 3;
            const float x0 = rp[0], x1 = rp[1], x2 = rp[2];
            const float dist =
                fmaxf(sqrtf(x0 * x0 + x1 * x1 + x2 * x2), 1e-8f);
            const float rs = (dist - median) * (dist - median);
            Xs[e][0] = (__bf16)x0;
            Xs[e][1] = (__bf16)x1;
            Xs[e][2] = (__bf16)x2;
            Xs[e][3] = (__bf16)dist;
            Xs[e][4] = (__bf16)rs;
            Xs[e][5] = (__bf16)(rs * rs);
            Xs[e][6] = (__bf16)(dist - contact);
        } else if (tid < 2 * BM) {
            const int e = tid - BM;
            const int tg = tgt[e0 + e];
            #pragma unroll
            for (int d = 0; d < FDOF; ++d)
                Xs[e][7 + d] = (__bf16)force[tg * FDOF + d];
        } else if (tid < 3 * BM) {
            const int e = tid - 2 * BM;
            const int sg = src[e0 + e];
            #pragma unroll
            for (int d = 0; d < FDOF; ++d)
                Xs[e][13 + d] = (__bf16)force[sg * FDOF + d];
        }
        __syncthreads();   // (B)

        // ---- layer 1: H1 = relu(X @ W1 + b1), wave w -> cols 32w..32w+31 ---
        #pragma unroll
        for (int m = 0; m < 4; ++m) {
            const bf16x8 a =
                *reinterpret_cast<const bf16x8*>(&Xs[m * 16 + l15][lhi * 8]);
            #pragma unroll
            for (int nb = 0; nb < 2; ++nb) {
                const float bv = nb ? b1v1 : b1v0;
                f32x4 acc = { bv, bv, bv, bv };
                acc = __builtin_amdgcn_mfma_f32_16x16x32_bf16(
                          a, w1f[nb], acc, 0, 0, 0);
                #pragma unroll
                for (int r = 0; r < 4; ++r)
                    H1s[m * 16 + lhi * 4 + r][(2 * w + nb) * 16 + l15] =
                        (__bf16)fmaxf(acc[r], 0.0f);
            }
        }
        __syncthreads();   // (C)

        // ---- layer 2: H2 = relu(H1 @ W2 + b2) ------------------------------
        #pragma unroll
        for (int m = 0; m < 4; ++m) {
            f32x4 acc0 = { b2v0, b2v0, b2v0, b2v0 };
            f32x4 acc1 = { b2v1, b2v1, b2v1, b2v1 };
            #pragma unroll
            for (int kt = 0; kt < 4; ++kt) {
                const bf16x8 a = *reinterpret_cast<const bf16x8*>(
                    &H1s[m * 16 + l15][kt * 32 + lhi * 8]);
                acc0 = __builtin_amdgcn_mfma_f32_16x16x32_bf16(
                           a, w2f[kt][0], acc0, 0, 0, 0);
                acc1 = __builtin_amdgcn_mfma_f32_16x16x32_bf16(
                           a, w2f[kt][1], acc1, 0, 0, 0);
            }
            #pragma unroll
            for (int r = 0; r < 4; ++r) {
                H2s[m * 16 + lhi * 4 + r][(2 * w) * 16 + l15] =
                    (__bf16)fmaxf(acc0[r], 0.0f);
                H2s[m * 16 + lhi * 4 + r][(2 * w + 1) * 16 + l15] =
                    (__bf16)fmaxf(acc1[r], 0.0f);
            }
        }
        __syncthreads();   // (D)

        // ---- layer 3: vel = (H2 @ W3 + b3)/mu; wave w -> edges 16w..16w+15 -
        f32x4 acc3 = { 0.0f, 0.0f, 0.0f, 0.0f };
        #pragma unroll
        for (int kt = 0; kt < 4; ++kt) {
            const bf16x8 a = *reinterpret_cast<const bf16x8*>(
                &H2s[w * 16 + l15][kt * 32 + lhi * 8]);
            acc3 = __builtin_amdgcn_mfma_f32_16x16x32_bf16(
                       a, w3f[kt], acc3, 0, 0, 0);
        }
        if (l15 < FDOF) {
            #pragma unroll
            for (int r = 0; r < 4; ++r) {
                const int e = w * 16 + lhi * 4 + r;
                atomicAdd(&out[(size_t)tgts[e] * FDOF + l15],
                          (acc3[r] + b3v) * inv_mu);
            }
        }
    }
}

extern "C" void kernel_launch(void* const* d_in, const int* in_sizes, int n_in,
                              void* d_out, int out_size, void* d_ws, size_t ws_size,
                              hipStream_t stream) {
    const float* rel   = (const float*)d_in[0];
    const int*   tgt   = (const int*)d_in[1];
    const int*   src   = (const int*)d_in[2];
    const float* force = (const float*)d_in[3];
    const float* visc  = (const float*)d_in[4];
    const float* med   = (const float*)d_in[5];
    const float* con   = (const float*)d_in[6];
    const float* W1    = (const float*)d_in[7];
    const float* b1    = (const float*)d_in[8];
    const float* W2    = (const float*)d_in[9];
    const float* b2    = (const float*)d_in[10];
    const float* W3    = (const float*)d_in[11];
    const float* b3    = (const float*)d_in[12];
    float* out = (float*)d_out;

    pairvel_zero_kernel<<<(out_size + 255) / 256, 256, 0, stream>>>(out, out_size);
    pairvel_mfma_kernel<<<GRID, 256, 0, stream>>>(
        rel, tgt, src, force, visc, med, con, W1, b1, W2, b2, W3, b3, out);
}